// Round 12
// baseline (1028.779 us; speedup 1.0000x reference)
//
#include <hip/hip_runtime.h>

#define H_ 8
#define B_ 8
#define S_ 2048
#define D_ 256

// padded LDS strides (halves): kill 8/16-way bank conflicts, keep 16B alignment
#define KSTRIDE 264   // k-tile rows (was 256): 528B = 4 banks offset/row
#define VSTRIDE 40    // 32-col tiles (was 32): 80B = 20 banks offset/row

typedef __attribute__((ext_vector_type(8))) _Float16 half8;
typedef __attribute__((ext_vector_type(4))) _Float16 half4v;
typedef __attribute__((ext_vector_type(4))) float f32x4;

// split 8 consecutive fp32 into fp16 hi + lo residual
__device__ inline void split8(const float* __restrict__ p, half8& hv, half8& lv) {
  float4 a = *(const float4*)p, b = *(const float4*)(p + 4);
  hv[0] = (_Float16)a.x; hv[1] = (_Float16)a.y; hv[2] = (_Float16)a.z; hv[3] = (_Float16)a.w;
  hv[4] = (_Float16)b.x; hv[5] = (_Float16)b.y; hv[6] = (_Float16)b.z; hv[7] = (_Float16)b.w;
  lv[0] = (_Float16)(a.x - (float)hv[0]); lv[1] = (_Float16)(a.y - (float)hv[1]);
  lv[2] = (_Float16)(a.z - (float)hv[2]); lv[3] = (_Float16)(a.w - (float)hv[3]);
  lv[4] = (_Float16)(b.x - (float)hv[4]); lv[5] = (_Float16)(b.y - (float)hv[5]);
  lv[6] = (_Float16)(b.z - (float)hv[6]); lv[7] = (_Float16)(b.w - (float)hv[7]);
}

// ------- transpose + split weights via LDS tile: W[h][f][d] -> Wt hi/lo [h][d][f] -------
__global__ void split_w_kernel(const float* __restrict__ W,
                               _Float16* __restrict__ thi, _Float16* __restrict__ tlo) {
  __shared__ float t[64][65];
  const int h = blockIdx.z, f0 = blockIdx.x * 64, d0 = blockIdx.y * 64;
  const int col = threadIdx.x & 63, rg = threadIdx.x >> 6;
#pragma unroll
  for (int it = 0; it < 16; ++it) {
    int f = rg * 16 + it;
    t[f][col] = W[((size_t)h * 256 + f0 + f) * 256 + d0 + col];
  }
  __syncthreads();
#pragma unroll
  for (int it = 0; it < 16; ++it) {
    int d = rg * 16 + it;
    float v = t[col][d];
    _Float16 hv = (_Float16)v;
    size_t idx = ((size_t)h * 256 + d0 + d) * 256 + f0 + col;
    thi[idx] = hv;
    tlo[idx] = (_Float16)(v - (float)hv);
  }
}

// ---------------- out = Cb broadcast ----------------
__global__ void out_init_kernel(float* __restrict__ out, const float* __restrict__ Cb) {
  int i = blockIdx.x * blockDim.x + threadIdx.x;
  if (i < B_ * S_ * 8) out[i] = Cb[i & 7];
}

// ---- q projection GEMM (R10's proven 128x128 3-mult): q = bo*Qw + Qb, write hi+lo ----
__global__ __launch_bounds__(256, 2) void proj_q_kernel(
    const float* __restrict__ A,
    const _Float16* __restrict__ Whi, const _Float16* __restrict__ Wlo,
    const float* __restrict__ bias, float oscale, int h0,
    _Float16* __restrict__ Ohi, _Float16* __restrict__ Olo) {
  __shared__ _Float16 a_hi[128 * VSTRIDE] __attribute__((aligned(16)));
  __shared__ _Float16 b_hi[128 * VSTRIDE] __attribute__((aligned(16)));
  __shared__ _Float16 a_lo[128 * VSTRIDE] __attribute__((aligned(16)));
  __shared__ _Float16 b_lo[128 * VSTRIDE] __attribute__((aligned(16)));
  const int tid = threadIdx.x;
  const int w = tid >> 6, lane = tid & 63;
  const int quad = lane >> 4, l15 = lane & 15;
  const int hb = blockIdx.z, h = h0 + (hb >> 3), b = hb & 7;
  const int s0 = blockIdx.x * 128, d0 = blockIdx.y * 128;
  const int wr = w >> 1, wc = w & 1;
  const f32x4 fz = {0.f, 0.f, 0.f, 0.f};
  f32x4 acc[4][4];
#pragma unroll
  for (int i = 0; i < 4; ++i)
#pragma unroll
    for (int j = 0; j < 4; ++j) acc[i][j] = fz;
  const size_t arow0 = (size_t)b * S_ + s0;
  const size_t wrow0 = (size_t)h * 256 + d0;
  for (int kk = 0; kk < 8; ++kk) {
    const int f0 = kk * 32;
    __syncthreads();
#pragma unroll
    for (int i = 0; i < 2; ++i) {
      int cc = i * 256 + tid;
      int r = cc >> 2, ch = (cc & 3) * 8;
      half8 hv, lv;
      split8(A + (arow0 + r) * 256 + f0 + ch, hv, lv);
      *(half8*)&a_hi[r * VSTRIDE + ch] = hv;
      *(half8*)&a_lo[r * VSTRIDE + ch] = lv;
      size_t woff = (wrow0 + r) * 256 + f0 + ch;
      *(half8*)&b_hi[r * VSTRIDE + ch] = *(const half8*)(Whi + woff);
      *(half8*)&b_lo[r * VSTRIDE + ch] = *(const half8*)(Wlo + woff);
    }
    __syncthreads();
    half8 afh[4], afl[4], bfh[4], bfl[4];
#pragma unroll
    for (int t = 0; t < 4; ++t) {
      int ar = wr * 64 + t * 16 + l15;
      afh[t] = *(const half8*)&a_hi[ar * VSTRIDE + quad * 8];
      afl[t] = *(const half8*)&a_lo[ar * VSTRIDE + quad * 8];
      int br = wc * 64 + t * 16 + l15;
      bfh[t] = *(const half8*)&b_hi[br * VSTRIDE + quad * 8];
      bfl[t] = *(const half8*)&b_lo[br * VSTRIDE + quad * 8];
    }
#pragma unroll
    for (int rf = 0; rf < 4; ++rf)
#pragma unroll
      for (int cf = 0; cf < 4; ++cf) {
        acc[rf][cf] = __builtin_amdgcn_mfma_f32_16x16x32_f16(afh[rf], bfh[cf], acc[rf][cf], 0, 0, 0);
        acc[rf][cf] = __builtin_amdgcn_mfma_f32_16x16x32_f16(afh[rf], bfl[cf], acc[rf][cf], 0, 0, 0);
        acc[rf][cf] = __builtin_amdgcn_mfma_f32_16x16x32_f16(afl[rf], bfh[cf], acc[rf][cf], 0, 0, 0);
      }
  }
#pragma unroll
  for (int rf = 0; rf < 4; ++rf) {
#pragma unroll
    for (int cf = 0; cf < 4; ++cf) {
      const int d = d0 + wc * 64 + cf * 16 + l15;
      const float bv = bias[h * 256 + d];
#pragma unroll
      for (int r = 0; r < 4; ++r) {
        const int s = s0 + wr * 64 + rf * 16 + quad * 4 + r;
        float val = (acc[rf][cf][r] + bv) * oscale;
        _Float16 hvv = (_Float16)val;
        size_t idx = ((size_t)hb * S_ + s) * 256 + d;
        Ohi[idx] = hvv;
        Olo[idx] = (_Float16)(val - (float)hvv);
      }
    }
  }
}

// ---- fused k+v projection (R12): shares A staging, halves proj barrier-rounds ----
// k: 3-mult hi/lo, write hi only [hb,S,D] (flash dropped qh*kl).
// v: single-mult hi*hi, write f16 transposed [hb,D,S], coalesced half4 stores.
// Per K-step: stage A(hi,lo)+Bk(hi,lo)+Bv(hi) [5 arrays, 51.2KB LDS], 64 MFMA.
// VGPR ~200-240 (acc 128) — fits 256 cap at 2 waves/SIMD. Spill tripwire: WRITE_SIZE.
__global__ __launch_bounds__(256, 2) void proj_kv_kernel(
    const float* __restrict__ A,
    const _Float16* __restrict__ Kwhi, const _Float16* __restrict__ Kwlo,
    const _Float16* __restrict__ Vwhi,
    const float* __restrict__ Kb, const float* __restrict__ Vb, int h0,
    _Float16* __restrict__ Ok, _Float16* __restrict__ Ovt) {
  __shared__ _Float16 a_hi[128 * VSTRIDE] __attribute__((aligned(16)));
  __shared__ _Float16 a_lo[128 * VSTRIDE] __attribute__((aligned(16)));
  __shared__ _Float16 bk_hi[128 * VSTRIDE] __attribute__((aligned(16)));
  __shared__ _Float16 bk_lo[128 * VSTRIDE] __attribute__((aligned(16)));
  __shared__ _Float16 bv_hi[128 * VSTRIDE] __attribute__((aligned(16)));
  const int tid = threadIdx.x;
  const int w = tid >> 6, lane = tid & 63;
  const int quad = lane >> 4, l15 = lane & 15;
  const int hb = blockIdx.z, h = h0 + (hb >> 3), b = hb & 7;
  const int s0 = blockIdx.x * 128, d0 = blockIdx.y * 128;
  const int wr = w >> 1, wc = w & 1;
  const f32x4 fz = {0.f, 0.f, 0.f, 0.f};
  f32x4 acck[4][4], accv[4][4];
#pragma unroll
  for (int i = 0; i < 4; ++i)
#pragma unroll
    for (int j = 0; j < 4; ++j) { acck[i][j] = fz; accv[i][j] = fz; }
  const size_t arow0 = (size_t)b * S_ + s0;
  const size_t wrow0 = (size_t)h * 256 + d0;
  for (int kk = 0; kk < 8; ++kk) {
    const int f0 = kk * 32;
    __syncthreads();
#pragma unroll
    for (int i = 0; i < 2; ++i) {
      int cc = i * 256 + tid;
      int r = cc >> 2, ch = (cc & 3) * 8;
      half8 hv, lv;
      split8(A + (arow0 + r) * 256 + f0 + ch, hv, lv);
      *(half8*)&a_hi[r * VSTRIDE + ch] = hv;
      *(half8*)&a_lo[r * VSTRIDE + ch] = lv;
      size_t woff = (wrow0 + r) * 256 + f0 + ch;
      *(half8*)&bk_hi[r * VSTRIDE + ch] = *(const half8*)(Kwhi + woff);
      *(half8*)&bk_lo[r * VSTRIDE + ch] = *(const half8*)(Kwlo + woff);
      *(half8*)&bv_hi[r * VSTRIDE + ch] = *(const half8*)(Vwhi + woff);
    }
    __syncthreads();
    half8 afh[4], afl[4];
#pragma unroll
    for (int t = 0; t < 4; ++t) {
      int ar = wr * 64 + t * 16 + l15;
      afh[t] = *(const half8*)&a_hi[ar * VSTRIDE + quad * 8];
      afl[t] = *(const half8*)&a_lo[ar * VSTRIDE + quad * 8];
    }
#pragma unroll
    for (int cf = 0; cf < 4; ++cf) {
      int br = wc * 64 + cf * 16 + l15;
      half8 bkh = *(const half8*)&bk_hi[br * VSTRIDE + quad * 8];
      half8 bkl = *(const half8*)&bk_lo[br * VSTRIDE + quad * 8];
      half8 bvh = *(const half8*)&bv_hi[br * VSTRIDE + quad * 8];
#pragma unroll
      for (int rf = 0; rf < 4; ++rf) {
        acck[rf][cf] = __builtin_amdgcn_mfma_f32_16x16x32_f16(afh[rf], bkh, acck[rf][cf], 0, 0, 0);
        acck[rf][cf] = __builtin_amdgcn_mfma_f32_16x16x32_f16(afh[rf], bkl, acck[rf][cf], 0, 0, 0);
        acck[rf][cf] = __builtin_amdgcn_mfma_f32_16x16x32_f16(afl[rf], bkh, acck[rf][cf], 0, 0, 0);
        accv[rf][cf] = __builtin_amdgcn_mfma_f32_16x16x32_f16(afh[rf], bvh, accv[rf][cf], 0, 0, 0);
      }
    }
  }
  // epilogue: C/D layout row = quad*4+reg (s), col = lane&15 (d)
#pragma unroll
  for (int rf = 0; rf < 4; ++rf) {
#pragma unroll
    for (int cf = 0; cf < 4; ++cf) {
      const int d = d0 + wc * 64 + cf * 16 + l15;
      const float bvK = Kb[h * 256 + d];
      const float bvV = Vb[h * 256 + d];
#pragma unroll
      for (int r = 0; r < 4; ++r) {
        const int s = s0 + wr * 64 + rf * 16 + quad * 4 + r;
        size_t idx = ((size_t)hb * S_ + s) * 256 + d;
        Ok[idx] = (_Float16)(acck[rf][cf][r] + bvK);
      }
      half4v pack;
#pragma unroll
      for (int r = 0; r < 4; ++r) pack[r] = (_Float16)(accv[rf][cf][r] + bvV);
      size_t vidx = ((size_t)hb * 256 + d) * S_ + s0 + wr * 64 + rf * 16 + quad * 4;
      *(half4v*)(Ovt + vidx) = pack;
    }
  }
}

// ---------------- flash attention + fused C-projection ----------------
// grid (32, HC*8). LDS-BW-bound: klo dropped (-33% LDS traffic; keeps register-resident
// ql*kh correction; absmax 56.0 < 62.7 threshold, deterministic — R9/R10 measured).
// 3 barriers per kt (P->PV phase barrier is load-bearing — R5).
// launch_bounds STAYS (256,2): R9's (256,3) capped VGPR at 84 -> 21MB spills, 496->675us.
__global__ __launch_bounds__(256, 2) void flash_kernel(
    const _Float16* __restrict__ qhi, const _Float16* __restrict__ qlo,
    const _Float16* __restrict__ khi,
    const _Float16* __restrict__ vt, const float* __restrict__ Cw,
    float* __restrict__ out, int h0) {
  __shared__ _Float16 khi_s[32 * KSTRIDE] __attribute__((aligned(16)));
  __shared__ _Float16 vt_s[256 * VSTRIDE] __attribute__((aligned(16)));
  __shared__ _Float16 p_s[4][16 * VSTRIDE] __attribute__((aligned(16)));
  const int tid = threadIdx.x, w = tid >> 6, lane = tid & 63;
  const int quad = lane >> 4, l15 = lane & 15;
  const int hb = blockIdx.y, h = h0 + (hb >> 3), b = hb & 7;
  const int qbase = blockIdx.x * 64;
  half8 qfh[8], qfl[8];
  {
    size_t qrow = (size_t)hb * S_ + qbase + w * 16 + l15;
    const _Float16* qh = qhi + qrow * 256 + quad * 8;
    const _Float16* ql = qlo + qrow * 256 + quad * 8;
#pragma unroll
    for (int ks = 0; ks < 8; ++ks) {
      qfh[ks] = *(const half8*)(qh + ks * 32);
      qfl[ks] = *(const half8*)(ql + ks * 32);
    }
  }
  const f32x4 fz = {0.f, 0.f, 0.f, 0.f};
  f32x4 o_acc[16];
#pragma unroll
  for (int df = 0; df < 16; ++df) o_acc[df] = fz;
  float m_r[4], l_r[4];
#pragma unroll
  for (int r = 0; r < 4; ++r) { m_r[r] = -3.0e38f; l_r[r] = 0.f; }

  for (int kt = 0; kt < 64; ++kt) {
    __syncthreads();
    {
      size_t kbase = ((size_t)hb * S_ + kt * 32) * 256;
#pragma unroll
      for (int i = 0; i < 4; ++i) {
        int cc = i * 256 + tid;
        int kr = cc >> 5, kch = (cc & 31) * 8;
        *(half8*)&khi_s[kr * KSTRIDE + kch] = *(const half8*)(khi + kbase + kr * 256 + kch);
        int vd = cc >> 2, vch = (cc & 3) * 8;
        size_t voff = ((size_t)hb * 256 + vd) * S_ + kt * 32 + vch;
        *(half8*)&vt_s[vd * VSTRIDE + vch] = *(const half8*)(vt + voff);
      }
    }
    __syncthreads();
    f32x4 sc0 = fz, sc1 = fz;
#pragma unroll
    for (int ks = 0; ks < 8; ++ks) {
      half8 bh0 = *(const half8*)&khi_s[(0 * 16 + l15) * KSTRIDE + ks * 32 + quad * 8];
      sc0 = __builtin_amdgcn_mfma_f32_16x16x32_f16(qfh[ks], bh0, sc0, 0, 0, 0);
      sc0 = __builtin_amdgcn_mfma_f32_16x16x32_f16(qfl[ks], bh0, sc0, 0, 0, 0);
      half8 bh1 = *(const half8*)&khi_s[(1 * 16 + l15) * KSTRIDE + ks * 32 + quad * 8];
      sc1 = __builtin_amdgcn_mfma_f32_16x16x32_f16(qfh[ks], bh1, sc1, 0, 0, 0);
      sc1 = __builtin_amdgcn_mfma_f32_16x16x32_f16(qfl[ks], bh1, sc1, 0, 0, 0);
    }
    float al[4], p0[4], p1[4];
#pragma unroll
    for (int r = 0; r < 4; ++r) {
      float v = fmaxf(sc0[r], sc1[r]);
      v = fmaxf(v, __shfl_xor(v, 1));
      v = fmaxf(v, __shfl_xor(v, 2));
      v = fmaxf(v, __shfl_xor(v, 4));
      v = fmaxf(v, __shfl_xor(v, 8));
      float mn = fmaxf(m_r[r], v);
      al[r] = __expf(m_r[r] - mn);
      m_r[r] = mn;
      p0[r] = __expf(sc0[r] - mn);
      p1[r] = __expf(sc1[r] - mn);
      float s = p0[r] + p1[r];
      s += __shfl_xor(s, 1);
      s += __shfl_xor(s, 2);
      s += __shfl_xor(s, 4);
      s += __shfl_xor(s, 8);
      l_r[r] = l_r[r] * al[r] + s;
    }
#pragma unroll
    for (int r = 0; r < 4; ++r) {
      p_s[w][(quad * 4 + r) * VSTRIDE + l15] = (_Float16)p0[r];
      p_s[w][(quad * 4 + r) * VSTRIDE + 16 + l15] = (_Float16)p1[r];
    }
#pragma unroll
    for (int df = 0; df < 16; ++df)
#pragma unroll
      for (int r = 0; r < 4; ++r) o_acc[df][r] *= al[r];
    __syncthreads();  // phase barrier: keeps softmax-shuffle and PV LDS phases aligned
    half8 pf = *(const half8*)&p_s[w][l15 * VSTRIDE + quad * 8];
#pragma unroll
    for (int df = 0; df < 16; ++df) {
      half8 vf = *(const half8*)&vt_s[(df * 16 + l15) * VSTRIDE + quad * 8];
      o_acc[df] = __builtin_amdgcn_mfma_f32_16x16x32_f16(pf, vf, o_acc[df], 0, 0, 0);
    }
  }
  float rcl[4];
#pragma unroll
  for (int r = 0; r < 4; ++r) rcl[r] = 1.0f / l_r[r];
  float part[32];
#pragma unroll
  for (int i = 0; i < 32; ++i) part[i] = 0.f;
#pragma unroll
  for (int df = 0; df < 16; ++df) {
    const float4* cwv = (const float4*)(Cw + ((size_t)h * 256 + df * 16 + l15) * 8);
    float4 c0 = cwv[0], c1 = cwv[1];
#pragma unroll
    for (int r = 0; r < 4; ++r) {
      float ov = o_acc[df][r] * rcl[r];
      part[r * 8 + 0] += ov * c0.x;
      part[r * 8 + 1] += ov * c0.y;
      part[r * 8 + 2] += ov * c0.z;
      part[r * 8 + 3] += ov * c0.w;
      part[r * 8 + 4] += ov * c1.x;
      part[r * 8 + 5] += ov * c1.y;
      part[r * 8 + 6] += ov * c1.z;
      part[r * 8 + 7] += ov * c1.w;
    }
  }
#pragma unroll
  for (int i = 0; i < 32; ++i) {
    float v = part[i];
    v += __shfl_xor(v, 1);
    v += __shfl_xor(v, 2);
    v += __shfl_xor(v, 4);
    v += __shfl_xor(v, 8);
    part[i] = v;
  }
  if (l15 == 0) {
#pragma unroll
    for (int r = 0; r < 4; ++r) {
      int s = qbase + w * 16 + quad * 4 + r;
#pragma unroll
      for (int j = 0; j < 8; ++j)
        atomicAdd(&out[((size_t)b * S_ + s) * 8 + j], part[r * 8 + j]);
    }
  }
}

extern "C" void kernel_launch(void* const* d_in, const int* in_sizes, int n_in,
                              void* d_out, int out_size, void* d_ws, size_t ws_size,
                              hipStream_t stream) {
  const float* x  = (const float*)d_in[0];
  const float* bo = (const float*)d_in[1];
  const float* Qw = (const float*)d_in[2];
  const float* Qb = (const float*)d_in[3];
  const float* Kw = (const float*)d_in[4];
  const float* Kb = (const float*)d_in[5];
  const float* Vw = (const float*)d_in[6];
  const float* Vb = (const float*)d_in[7];
  const float* Cw = (const float*)d_in[8];
  const float* Cb = (const float*)d_in[9];
  float* out = (float*)d_out;

  const size_t NW  = (size_t)H_ * 256 * 256;
  const size_t NHB = (size_t)B_ * S_ * 256;
  const size_t ALN = 256;
  auto pad = [](size_t b) { return (b + 255) & ~(size_t)255; };

  // pick largest head-chunk HC in {8,4,2,1} whose scratch fits ws_size
  int HC = 8;
  while (HC > 1) {
    size_t need = 6 * pad(NW * 2) + 4 * pad((size_t)HC * NHB * 2) + ALN;
    if (need <= ws_size) break;
    HC >>= 1;
  }

  char* base = (char*)d_ws;
  size_t off = 0;
  auto carve = [&](size_t nelem) -> _Float16* {
    _Float16* p = (_Float16*)(base + off);
    off += pad(nelem * 2);
    return p;
  };
  _Float16* qwt_hi = carve(NW); _Float16* qwt_lo = carve(NW);
  _Float16* kwt_hi = carve(NW); _Float16* kwt_lo = carve(NW);
  _Float16* vwt_hi = carve(NW); _Float16* vwt_lo = carve(NW);
  const size_t NC = (size_t)HC * NHB;
  _Float16* q_hi = carve(NC); _Float16* q_lo = carve(NC);
  _Float16* k_hi = carve(NC);
  _Float16* v_t  = carve(NC);

  dim3 wg(4, 4, 8);
  split_w_kernel<<<wg, 256, 0, stream>>>(Qw, qwt_hi, qwt_lo);
  split_w_kernel<<<wg, 256, 0, stream>>>(Kw, kwt_hi, kwt_lo);
  split_w_kernel<<<wg, 256, 0, stream>>>(Vw, vwt_hi, vwt_lo);
  out_init_kernel<<<(B_ * S_ * 8) / 256, 256, 0, stream>>>(out, Cb);

  for (int h0 = 0; h0 < H_; h0 += HC) {
    dim3 pg(16, 2, HC * 8);   // 128x128 tiles (R10's best-measured proj shape)
    // q: fold softmax scale 1/sqrt(256)=1/16 into the projection output
    proj_q_kernel<<<pg, 256, 0, stream>>>(bo, qwt_hi, qwt_lo, Qb, 0.0625f, h0, q_hi, q_lo);
    proj_kv_kernel<<<pg, 256, 0, stream>>>(x, kwt_hi, kwt_lo, vwt_hi, Kb, Vb, h0, k_hi, v_t);
    dim3 fg(32, HC * 8);
    flash_kernel<<<fg, 256, 0, stream>>>(q_hi, q_lo, k_hi, v_t, Cw, out, h0);
  }
}

// Round 13
// 1018.346 us; speedup vs baseline: 1.0102x; 1.0102x over previous
//
#include <hip/hip_runtime.h>

#define H_ 8
#define B_ 8
#define S_ 2048
#define D_ 256

// padded LDS strides (halves): kill 8/16-way bank conflicts, keep 16B alignment
#define KSTRIDE 264   // k-tile rows: 528B = 4 banks offset/row
#define VSTRIDE 40    // 32-col tiles: 80B = 20 banks offset/row

typedef __attribute__((ext_vector_type(8))) _Float16 half8;
typedef __attribute__((ext_vector_type(4))) _Float16 half4v;
typedef __attribute__((ext_vector_type(4))) float f32x4;

// split 8 consecutive fp32 into fp16 hi + lo residual
__device__ inline void split8(const float* __restrict__ p, half8& hv, half8& lv) {
  float4 a = *(const float4*)p, b = *(const float4*)(p + 4);
  hv[0] = (_Float16)a.x; hv[1] = (_Float16)a.y; hv[2] = (_Float16)a.z; hv[3] = (_Float16)a.w;
  hv[4] = (_Float16)b.x; hv[5] = (_Float16)b.y; hv[6] = (_Float16)b.z; hv[7] = (_Float16)b.w;
  lv[0] = (_Float16)(a.x - (float)hv[0]); lv[1] = (_Float16)(a.y - (float)hv[1]);
  lv[2] = (_Float16)(a.z - (float)hv[2]); lv[3] = (_Float16)(a.w - (float)hv[3]);
  lv[4] = (_Float16)(b.x - (float)hv[4]); lv[5] = (_Float16)(b.y - (float)hv[5]);
  lv[6] = (_Float16)(b.z - (float)hv[6]); lv[7] = (_Float16)(b.w - (float)hv[7]);
}

// ------- transpose + split weights via LDS tile: W[h][f][d] -> Wt hi/lo [h][d][f] -------
__global__ void split_w_kernel(const float* __restrict__ W,
                               _Float16* __restrict__ thi, _Float16* __restrict__ tlo) {
  __shared__ float t[64][65];
  const int h = blockIdx.z, f0 = blockIdx.x * 64, d0 = blockIdx.y * 64;
  const int col = threadIdx.x & 63, rg = threadIdx.x >> 6;
#pragma unroll
  for (int it = 0; it < 16; ++it) {
    int f = rg * 16 + it;
    t[f][col] = W[((size_t)h * 256 + f0 + f) * 256 + d0 + col];
  }
  __syncthreads();
#pragma unroll
  for (int it = 0; it < 16; ++it) {
    int d = rg * 16 + it;
    float v = t[col][d];
    _Float16 hv = (_Float16)v;
    size_t idx = ((size_t)h * 256 + d0 + d) * 256 + f0 + col;
    thi[idx] = hv;
    tlo[idx] = (_Float16)(v - (float)hv);
  }
}

// ---------------- out = Cb broadcast ----------------
__global__ void out_init_kernel(float* __restrict__ out, const float* __restrict__ Cb) {
  int i = blockIdx.x * blockDim.x + threadIdx.x;
  if (i < B_ * S_ * 8) out[i] = Cb[i & 7];
}

// ---- projection GEMM (R10's best-measured config, frozen): 128x128 tiles ----
// Template VMODE: 0: 3-mult, write hi+lo (q). 2: 3-mult, write hi only (k).
//                 1: single-mult, write f16 transposed [hb,D,S] (v).
template <int VMODE>
__global__ __launch_bounds__(256, 2) void proj_kernel(
    const float* __restrict__ A,
    const _Float16* __restrict__ Whi, const _Float16* __restrict__ Wlo,
    const float* __restrict__ bias, float oscale, int h0,
    _Float16* __restrict__ Ohi, _Float16* __restrict__ Olo) {
  constexpr bool TMULT = (VMODE != 1);
  __shared__ _Float16 a_hi[128 * VSTRIDE] __attribute__((aligned(16)));
  __shared__ _Float16 b_hi[128 * VSTRIDE] __attribute__((aligned(16)));
  __shared__ _Float16 a_lo[TMULT ? 128 * VSTRIDE : 8] __attribute__((aligned(16)));
  __shared__ _Float16 b_lo[TMULT ? 128 * VSTRIDE : 8] __attribute__((aligned(16)));
  const int tid = threadIdx.x;
  const int w = tid >> 6, lane = tid & 63;
  const int quad = lane >> 4, l15 = lane & 15;
  const int hb = blockIdx.z, h = h0 + (hb >> 3), b = hb & 7;
  const int s0 = blockIdx.x * 128, d0 = blockIdx.y * 128;
  const int wr = w >> 1, wc = w & 1;
  const f32x4 fz = {0.f, 0.f, 0.f, 0.f};
  f32x4 acc[4][4];
#pragma unroll
  for (int i = 0; i < 4; ++i)
#pragma unroll
    for (int j = 0; j < 4; ++j) acc[i][j] = fz;
  const size_t arow0 = (size_t)b * S_ + s0;
  const size_t wrow0 = (size_t)h * 256 + d0;
  for (int kk = 0; kk < 8; ++kk) {
    const int f0 = kk * 32;
    __syncthreads();
#pragma unroll
    for (int i = 0; i < 2; ++i) {
      int cc = i * 256 + tid;
      int r = cc >> 2, ch = (cc & 3) * 8;
      half8 hv, lv;
      split8(A + (arow0 + r) * 256 + f0 + ch, hv, lv);
      *(half8*)&a_hi[r * VSTRIDE + ch] = hv;
      size_t woff = (wrow0 + r) * 256 + f0 + ch;
      *(half8*)&b_hi[r * VSTRIDE + ch] = *(const half8*)(Whi + woff);
      if (TMULT) {
        *(half8*)&a_lo[r * VSTRIDE + ch] = lv;
        *(half8*)&b_lo[r * VSTRIDE + ch] = *(const half8*)(Wlo + woff);
      }
    }
    __syncthreads();
    half8 afh[4], afl[4], bfh[4], bfl[4];
#pragma unroll
    for (int t = 0; t < 4; ++t) {
      int ar = wr * 64 + t * 16 + l15;
      afh[t] = *(const half8*)&a_hi[ar * VSTRIDE + quad * 8];
      int br = wc * 64 + t * 16 + l15;
      bfh[t] = *(const half8*)&b_hi[br * VSTRIDE + quad * 8];
      if (TMULT) {
        afl[t] = *(const half8*)&a_lo[ar * VSTRIDE + quad * 8];
        bfl[t] = *(const half8*)&b_lo[br * VSTRIDE + quad * 8];
      }
    }
#pragma unroll
    for (int rf = 0; rf < 4; ++rf)
#pragma unroll
      for (int cf = 0; cf < 4; ++cf) {
        acc[rf][cf] = __builtin_amdgcn_mfma_f32_16x16x32_f16(afh[rf], bfh[cf], acc[rf][cf], 0, 0, 0);
        if (TMULT) {
          acc[rf][cf] = __builtin_amdgcn_mfma_f32_16x16x32_f16(afh[rf], bfl[cf], acc[rf][cf], 0, 0, 0);
          acc[rf][cf] = __builtin_amdgcn_mfma_f32_16x16x32_f16(afl[rf], bfh[cf], acc[rf][cf], 0, 0, 0);
        }
      }
  }
#pragma unroll
  for (int rf = 0; rf < 4; ++rf) {
#pragma unroll
    for (int cf = 0; cf < 4; ++cf) {
      const int d = d0 + wc * 64 + cf * 16 + l15;
      const float bv = bias[h * 256 + d];
      if (VMODE != 1) {
#pragma unroll
        for (int r = 0; r < 4; ++r) {
          const int s = s0 + wr * 64 + rf * 16 + quad * 4 + r;
          float val = (acc[rf][cf][r] + bv) * oscale;
          _Float16 hvv = (_Float16)val;
          size_t idx = ((size_t)hb * S_ + s) * 256 + d;
          Ohi[idx] = hvv;
          if (VMODE == 0) Olo[idx] = (_Float16)(val - (float)hvv);
        }
      } else {
        half4v pack;
#pragma unroll
        for (int r = 0; r < 4; ++r) pack[r] = (_Float16)((acc[rf][cf][r] + bv) * oscale);
        size_t idx = ((size_t)hb * 256 + d) * S_ + s0 + wr * 64 + rf * 16 + quad * 4;
        *(half4v*)(Ohi + idx) = pack;
      }
    }
  }
}

// ---------------- flash attention + fused C-projection ----------------
// R13: PV computes O^T (A = V^T d-strip per wave, B = P^T from all 4 p_s buffers) —
// removes the 4x cross-wave duplication of V-fragment LDS reads (68KB -> 32KB per
// block-iter; total 196 -> 160KB). QK/softmax unchanged. alpha & 1/l redistributed
// via small LDS arrays (broadcast reads, free). Barrier C now semantically required
// (cross-wave p_s reads) — it was already load-bearing (R5).
// klo dropped (R9/R10: absmax 56 < 62.7). launch_bounds stays (256,2) (R9 lesson).
__global__ __launch_bounds__(256, 2) void flash_kernel(
    const _Float16* __restrict__ qhi, const _Float16* __restrict__ qlo,
    const _Float16* __restrict__ khi,
    const _Float16* __restrict__ vt, const float* __restrict__ Cw,
    float* __restrict__ out, int h0) {
  __shared__ _Float16 khi_s[32 * KSTRIDE] __attribute__((aligned(16)));
  __shared__ _Float16 vt_s[256 * VSTRIDE] __attribute__((aligned(16)));
  __shared__ _Float16 p_s[4][16 * VSTRIDE] __attribute__((aligned(16)));
  __shared__ float al_s[64];
  __shared__ float rl_s[64];
  const int tid = threadIdx.x, w = tid >> 6, lane = tid & 63;
  const int quad = lane >> 4, l15 = lane & 15;
  const int hb = blockIdx.y, h = h0 + (hb >> 3), b = hb & 7;
  const int qbase = blockIdx.x * 64;
  // q fragments in registers (softmax scale 1/16 folded into q projection)
  half8 qfh[8], qfl[8];
  {
    size_t qrow = (size_t)hb * S_ + qbase + w * 16 + l15;
    const _Float16* qh = qhi + qrow * 256 + quad * 8;
    const _Float16* ql = qlo + qrow * 256 + quad * 8;
#pragma unroll
    for (int ks = 0; ks < 8; ++ks) {
      qfh[ks] = *(const half8*)(qh + ks * 32);
      qfl[ks] = *(const half8*)(ql + ks * 32);
    }
  }
  const f32x4 fz = {0.f, 0.f, 0.f, 0.f};
  // o_acc[dtl][st]: O^T tile — d = w*64 + dtl*16 + quad*4 + reg, s(block) = st*16 + l15
  f32x4 o_acc[4][4];
#pragma unroll
  for (int i = 0; i < 4; ++i)
#pragma unroll
    for (int j = 0; j < 4; ++j) o_acc[i][j] = fz;
  float m_r[4], l_r[4];  // softmax state for s = w*16 + quad*4 + r (unchanged)
#pragma unroll
  for (int r = 0; r < 4; ++r) { m_r[r] = -3.0e38f; l_r[r] = 0.f; }

  for (int kt = 0; kt < 64; ++kt) {
    __syncthreads();  // A: prior PV reads of vt_s done before overwrite
    {
      size_t kbase = ((size_t)hb * S_ + kt * 32) * 256;
#pragma unroll
      for (int i = 0; i < 4; ++i) {
        int cc = i * 256 + tid;
        int kr = cc >> 5, kch = (cc & 31) * 8;
        *(half8*)&khi_s[kr * KSTRIDE + kch] = *(const half8*)(khi + kbase + kr * 256 + kch);
        int vd = cc >> 2, vch = (cc & 3) * 8;
        size_t voff = ((size_t)hb * 256 + vd) * S_ + kt * 32 + vch;
        *(half8*)&vt_s[vd * VSTRIDE + vch] = *(const half8*)(vt + voff);
      }
    }
    __syncthreads();  // B: staging visible
    // QK^T: 2-mult (qh+ql)*kh, scores for 16 q-rows x 32 k-cols per wave
    f32x4 sc0 = fz, sc1 = fz;
#pragma unroll
    for (int ks = 0; ks < 8; ++ks) {
      half8 bh0 = *(const half8*)&khi_s[(0 * 16 + l15) * KSTRIDE + ks * 32 + quad * 8];
      sc0 = __builtin_amdgcn_mfma_f32_16x16x32_f16(qfh[ks], bh0, sc0, 0, 0, 0);
      sc0 = __builtin_amdgcn_mfma_f32_16x16x32_f16(qfl[ks], bh0, sc0, 0, 0, 0);
      half8 bh1 = *(const half8*)&khi_s[(1 * 16 + l15) * KSTRIDE + ks * 32 + quad * 8];
      sc1 = __builtin_amdgcn_mfma_f32_16x16x32_f16(qfh[ks], bh1, sc1, 0, 0, 0);
      sc1 = __builtin_amdgcn_mfma_f32_16x16x32_f16(qfl[ks], bh1, sc1, 0, 0, 0);
    }
    // online softmax; C/D layout: row = quad*4+r, col = lane&15
    float al[4], p0[4], p1[4];
#pragma unroll
    for (int r = 0; r < 4; ++r) {
      float v = fmaxf(sc0[r], sc1[r]);
      v = fmaxf(v, __shfl_xor(v, 1));
      v = fmaxf(v, __shfl_xor(v, 2));
      v = fmaxf(v, __shfl_xor(v, 4));
      v = fmaxf(v, __shfl_xor(v, 8));
      float mn = fmaxf(m_r[r], v);
      al[r] = __expf(m_r[r] - mn);
      m_r[r] = mn;
      p0[r] = __expf(sc0[r] - mn);
      p1[r] = __expf(sc1[r] - mn);
      float s = p0[r] + p1[r];
      s += __shfl_xor(s, 1);
      s += __shfl_xor(s, 2);
      s += __shfl_xor(s, 4);
      s += __shfl_xor(s, 8);
      l_r[r] = l_r[r] * al[r] + s;
    }
    // P -> LDS (C-layout write) + alpha broadcast
#pragma unroll
    for (int r = 0; r < 4; ++r) {
      p_s[w][(quad * 4 + r) * VSTRIDE + l15] = (_Float16)p0[r];
      p_s[w][(quad * 4 + r) * VSTRIDE + 16 + l15] = (_Float16)p1[r];
    }
    if (l15 == 0) {
#pragma unroll
      for (int r = 0; r < 4; ++r) al_s[w * 16 + quad * 4 + r] = al[r];
    }
    __syncthreads();  // C: p_s + al_s visible to all waves (cross-wave reads below)
    // PV as O^T: A = V^T rows of wave's d-strip, B = P^T from p_s[st]
    float al_t[4];
#pragma unroll
    for (int st = 0; st < 4; ++st) al_t[st] = al_s[st * 16 + l15];
#pragma unroll
    for (int dtl = 0; dtl < 4; ++dtl)
#pragma unroll
      for (int st = 0; st < 4; ++st)
#pragma unroll
        for (int c = 0; c < 4; ++c) o_acc[dtl][st][c] *= al_t[st];
    half8 pf[4];
#pragma unroll
    for (int st = 0; st < 4; ++st)
      pf[st] = *(const half8*)&p_s[st][l15 * VSTRIDE + quad * 8];
#pragma unroll
    for (int dtl = 0; dtl < 4; ++dtl) {
      half8 vf = *(const half8*)&vt_s[(w * 64 + dtl * 16 + l15) * VSTRIDE + quad * 8];
#pragma unroll
      for (int st = 0; st < 4; ++st)
        o_acc[dtl][st] = __builtin_amdgcn_mfma_f32_16x16x32_f16(vf, pf[st], o_acc[dtl][st], 0, 0, 0);
    }
  }
  // redistribute 1/l to O^T layout
  if (l15 == 0) {
#pragma unroll
    for (int r = 0; r < 4; ++r) rl_s[w * 16 + quad * 4 + r] = 1.0f / l_r[r];
  }
  __syncthreads();
  float rl_t[4];
#pragma unroll
  for (int st = 0; st < 4; ++st) rl_t[st] = rl_s[st * 16 + l15];
  // epilogue: out[b, qbase+st*16+l15, j] += sum_{d in wave strip} o * Cw[h*256+d][j]
  float part[4][8];
#pragma unroll
  for (int st = 0; st < 4; ++st)
#pragma unroll
    for (int j = 0; j < 8; ++j) part[st][j] = 0.f;
#pragma unroll
  for (int dtl = 0; dtl < 4; ++dtl) {
#pragma unroll
    for (int r = 0; r < 4; ++r) {
      const int d = w * 64 + dtl * 16 + quad * 4 + r;
      const float4* cwv = (const float4*)(Cw + ((size_t)h * 256 + d) * 8);
      float4 c0 = cwv[0], c1 = cwv[1];
#pragma unroll
      for (int st = 0; st < 4; ++st) {
        float ov = o_acc[dtl][st][r];
        part[st][0] += ov * c0.x; part[st][1] += ov * c0.y;
        part[st][2] += ov * c0.z; part[st][3] += ov * c0.w;
        part[st][4] += ov * c1.x; part[st][5] += ov * c1.y;
        part[st][6] += ov * c1.z; part[st][7] += ov * c1.w;
      }
    }
  }
#pragma unroll
  for (int st = 0; st < 4; ++st)
#pragma unroll
    for (int j = 0; j < 8; ++j) {
      float v = part[st][j] * rl_t[st];
      v += __shfl_xor(v, 16);   // reduce across quads (d-subranges)
      v += __shfl_xor(v, 32);
      if (quad == 0)
        atomicAdd(&out[((size_t)b * S_ + qbase + st * 16 + l15) * 8 + j], v);
    }
}

extern "C" void kernel_launch(void* const* d_in, const int* in_sizes, int n_in,
                              void* d_out, int out_size, void* d_ws, size_t ws_size,
                              hipStream_t stream) {
  const float* x  = (const float*)d_in[0];
  const float* bo = (const float*)d_in[1];
  const float* Qw = (const float*)d_in[2];
  const float* Qb = (const float*)d_in[3];
  const float* Kw = (const float*)d_in[4];
  const float* Kb = (const float*)d_in[5];
  const float* Vw = (const float*)d_in[6];
  const float* Vb = (const float*)d_in[7];
  const float* Cw = (const float*)d_in[8];
  const float* Cb = (const float*)d_in[9];
  float* out = (float*)d_out;

  const size_t NW  = (size_t)H_ * 256 * 256;
  const size_t NHB = (size_t)B_ * S_ * 256;
  const size_t ALN = 256;
  auto pad = [](size_t b) { return (b + 255) & ~(size_t)255; };

  int HC = 8;
  while (HC > 1) {
    size_t need = 6 * pad(NW * 2) + 4 * pad((size_t)HC * NHB * 2) + ALN;
    if (need <= ws_size) break;
    HC >>= 1;
  }

  char* base = (char*)d_ws;
  size_t off = 0;
  auto carve = [&](size_t nelem) -> _Float16* {
    _Float16* p = (_Float16*)(base + off);
    off += pad(nelem * 2);
    return p;
  };
  _Float16* qwt_hi = carve(NW); _Float16* qwt_lo = carve(NW);
  _Float16* kwt_hi = carve(NW); _Float16* kwt_lo = carve(NW);
  _Float16* vwt_hi = carve(NW); _Float16* vwt_lo = carve(NW);
  const size_t NC = (size_t)HC * NHB;
  _Float16* q_hi = carve(NC); _Float16* q_lo = carve(NC);
  _Float16* k_hi = carve(NC);
  _Float16* v_t  = carve(NC);

  dim3 wg(4, 4, 8);
  split_w_kernel<<<wg, 256, 0, stream>>>(Qw, qwt_hi, qwt_lo);
  split_w_kernel<<<wg, 256, 0, stream>>>(Kw, kwt_hi, kwt_lo);
  split_w_kernel<<<wg, 256, 0, stream>>>(Vw, vwt_hi, vwt_lo);
  out_init_kernel<<<(B_ * S_ * 8) / 256, 256, 0, stream>>>(out, Cb);

  for (int h0 = 0; h0 < H_; h0 += HC) {
    dim3 pg(16, 2, HC * 8);   // R10's best-measured proj config (frozen)
    proj_kernel<0><<<pg, 256, 0, stream>>>(bo, qwt_hi, qwt_lo, Qb, 0.0625f, h0, q_hi, q_lo);
    proj_kernel<2><<<pg, 256, 0, stream>>>(x, kwt_hi, kwt_lo, Kb, 1.0f, h0, k_hi, nullptr);
    proj_kernel<1><<<pg, 256, 0, stream>>>(x, vwt_hi, vwt_lo, Vb, 1.0f, h0, v_t, nullptr);
    dim3 fg(32, HC * 8);
    flash_kernel<<<fg, 256, 0, stream>>>(q_hi, q_lo, k_hi, v_t, Cw, out, h0);
  }
}

// Round 14
// 967.561 us; speedup vs baseline: 1.0633x; 1.0525x over previous
//
#include <hip/hip_runtime.h>

#define H_ 8
#define B_ 8
#define S_ 2048
#define D_ 256

// padded LDS strides (halves): kill 8/16-way bank conflicts, keep 16B alignment
#define KSTRIDE 264   // k-tile rows: 528B = 4 banks offset/row
#define VSTRIDE 40    // 32-col tiles: 80B = 20 banks offset/row

typedef __attribute__((ext_vector_type(8))) _Float16 half8;
typedef __attribute__((ext_vector_type(4))) _Float16 half4v;
typedef __attribute__((ext_vector_type(4))) float f32x4;

// split 8 consecutive fp32 into fp16 hi + lo residual
__device__ inline void split8(const float* __restrict__ p, half8& hv, half8& lv) {
  float4 a = *(const float4*)p, b = *(const float4*)(p + 4);
  hv[0] = (_Float16)a.x; hv[1] = (_Float16)a.y; hv[2] = (_Float16)a.z; hv[3] = (_Float16)a.w;
  hv[4] = (_Float16)b.x; hv[5] = (_Float16)b.y; hv[6] = (_Float16)b.z; hv[7] = (_Float16)b.w;
  lv[0] = (_Float16)(a.x - (float)hv[0]); lv[1] = (_Float16)(a.y - (float)hv[1]);
  lv[2] = (_Float16)(a.z - (float)hv[2]); lv[3] = (_Float16)(a.w - (float)hv[3]);
  lv[4] = (_Float16)(b.x - (float)hv[4]); lv[5] = (_Float16)(b.y - (float)hv[5]);
  lv[6] = (_Float16)(b.z - (float)hv[6]); lv[7] = (_Float16)(b.w - (float)hv[7]);
}

// ------- transpose + split weights via LDS tile: W[h][f][d] -> Wt hi/lo [h][d][f] -------
__global__ void split_w_kernel(const float* __restrict__ W,
                               _Float16* __restrict__ thi, _Float16* __restrict__ tlo) {
  __shared__ float t[64][65];
  const int h = blockIdx.z, f0 = blockIdx.x * 64, d0 = blockIdx.y * 64;
  const int col = threadIdx.x & 63, rg = threadIdx.x >> 6;
#pragma unroll
  for (int it = 0; it < 16; ++it) {
    int f = rg * 16 + it;
    t[f][col] = W[((size_t)h * 256 + f0 + f) * 256 + d0 + col];
  }
  __syncthreads();
#pragma unroll
  for (int it = 0; it < 16; ++it) {
    int d = rg * 16 + it;
    float v = t[col][d];
    _Float16 hv = (_Float16)v;
    size_t idx = ((size_t)h * 256 + d0 + d) * 256 + f0 + col;
    thi[idx] = hv;
    tlo[idx] = (_Float16)(v - (float)hv);
  }
}

// ---------------- out = Cb broadcast ----------------
__global__ void out_init_kernel(float* __restrict__ out, const float* __restrict__ Cb) {
  int i = blockIdx.x * blockDim.x + threadIdx.x;
  if (i < B_ * S_ * 8) out[i] = Cb[i & 7];
}

// ---- projection GEMM (R10's best-measured config — FROZEN) ----
// 128x128 tiles. Latency-bound at ~10x memory floor; resistant to prefetch (R4/R7),
// occupancy (R7/R9), smaller tiles (R11), kv-fusion (R12) — all measured neutral/worse.
// Template VMODE: 0: 3-mult, write hi+lo (q). 2: 3-mult, write hi only (k).
//                 1: single-mult, write f16 transposed [hb,D,S] (v).
template <int VMODE>
__global__ __launch_bounds__(256, 2) void proj_kernel(
    const float* __restrict__ A,
    const _Float16* __restrict__ Whi, const _Float16* __restrict__ Wlo,
    const float* __restrict__ bias, float oscale, int h0,
    _Float16* __restrict__ Ohi, _Float16* __restrict__ Olo) {
  constexpr bool TMULT = (VMODE != 1);
  __shared__ _Float16 a_hi[128 * VSTRIDE] __attribute__((aligned(16)));
  __shared__ _Float16 b_hi[128 * VSTRIDE] __attribute__((aligned(16)));
  __shared__ _Float16 a_lo[TMULT ? 128 * VSTRIDE : 8] __attribute__((aligned(16)));
  __shared__ _Float16 b_lo[TMULT ? 128 * VSTRIDE : 8] __attribute__((aligned(16)));
  const int tid = threadIdx.x;
  const int w = tid >> 6, lane = tid & 63;
  const int quad = lane >> 4, l15 = lane & 15;
  const int hb = blockIdx.z, h = h0 + (hb >> 3), b = hb & 7;
  const int s0 = blockIdx.x * 128, d0 = blockIdx.y * 128;
  const int wr = w >> 1, wc = w & 1;
  const f32x4 fz = {0.f, 0.f, 0.f, 0.f};
  f32x4 acc[4][4];
#pragma unroll
  for (int i = 0; i < 4; ++i)
#pragma unroll
    for (int j = 0; j < 4; ++j) acc[i][j] = fz;
  const size_t arow0 = (size_t)b * S_ + s0;
  const size_t wrow0 = (size_t)h * 256 + d0;
  for (int kk = 0; kk < 8; ++kk) {
    const int f0 = kk * 32;
    __syncthreads();
#pragma unroll
    for (int i = 0; i < 2; ++i) {
      int cc = i * 256 + tid;
      int r = cc >> 2, ch = (cc & 3) * 8;
      half8 hv, lv;
      split8(A + (arow0 + r) * 256 + f0 + ch, hv, lv);
      *(half8*)&a_hi[r * VSTRIDE + ch] = hv;
      size_t woff = (wrow0 + r) * 256 + f0 + ch;
      *(half8*)&b_hi[r * VSTRIDE + ch] = *(const half8*)(Whi + woff);
      if (TMULT) {
        *(half8*)&a_lo[r * VSTRIDE + ch] = lv;
        *(half8*)&b_lo[r * VSTRIDE + ch] = *(const half8*)(Wlo + woff);
      }
    }
    __syncthreads();
    half8 afh[4], afl[4], bfh[4], bfl[4];
#pragma unroll
    for (int t = 0; t < 4; ++t) {
      int ar = wr * 64 + t * 16 + l15;
      afh[t] = *(const half8*)&a_hi[ar * VSTRIDE + quad * 8];
      int br = wc * 64 + t * 16 + l15;
      bfh[t] = *(const half8*)&b_hi[br * VSTRIDE + quad * 8];
      if (TMULT) {
        afl[t] = *(const half8*)&a_lo[ar * VSTRIDE + quad * 8];
        bfl[t] = *(const half8*)&b_lo[br * VSTRIDE + quad * 8];
      }
    }
#pragma unroll
    for (int rf = 0; rf < 4; ++rf)
#pragma unroll
      for (int cf = 0; cf < 4; ++cf) {
        acc[rf][cf] = __builtin_amdgcn_mfma_f32_16x16x32_f16(afh[rf], bfh[cf], acc[rf][cf], 0, 0, 0);
        if (TMULT) {
          acc[rf][cf] = __builtin_amdgcn_mfma_f32_16x16x32_f16(afh[rf], bfl[cf], acc[rf][cf], 0, 0, 0);
          acc[rf][cf] = __builtin_amdgcn_mfma_f32_16x16x32_f16(afl[rf], bfh[cf], acc[rf][cf], 0, 0, 0);
        }
      }
  }
  // epilogue: C/D layout row = quad*4+reg (s), col = lane&15 (d)
#pragma unroll
  for (int rf = 0; rf < 4; ++rf) {
#pragma unroll
    for (int cf = 0; cf < 4; ++cf) {
      const int d = d0 + wc * 64 + cf * 16 + l15;
      const float bv = bias[h * 256 + d];
      if (VMODE != 1) {
#pragma unroll
        for (int r = 0; r < 4; ++r) {
          const int s = s0 + wr * 64 + rf * 16 + quad * 4 + r;
          float val = (acc[rf][cf][r] + bv) * oscale;
          _Float16 hvv = (_Float16)val;
          size_t idx = ((size_t)hb * S_ + s) * 256 + d;
          Ohi[idx] = hvv;
          if (VMODE == 0) Olo[idx] = (_Float16)(val - (float)hvv);
        }
      } else {
        // lane holds 4 consecutive s for fixed d -> coalesced half4 store along S
        half4v pack;
#pragma unroll
        for (int r = 0; r < 4; ++r) pack[r] = (_Float16)((acc[rf][cf][r] + bv) * oscale);
        size_t idx = ((size_t)hb * 256 + d) * S_ + s0 + wr * 64 + rf * 16 + quad * 4;
        *(half4v*)(Ohi + idx) = pack;
      }
    }
  }
}

// ---------------- flash attention + fused C-projection (R10 config — FROZEN) ----------------
// grid (32, HC*8). klo dropped (-33% LDS traffic, absmax 56 < 62.7 — R9/R10).
// 3 barriers per kt: P->PV phase barrier is load-bearing (R5: removing cost 1.5x).
// launch_bounds (256,2): (256,3) capped VGPR at 84 -> 21MB spills (R9).
// O^T/PV-dedup variant measured WORSE (R13: +48MB atomic RMW, +cross-wave lgkm waits).
// Model: ~80% LDS-BW-saturated; remaining QK B-read duplication is structural.
__global__ __launch_bounds__(256, 2) void flash_kernel(
    const _Float16* __restrict__ qhi, const _Float16* __restrict__ qlo,
    const _Float16* __restrict__ khi,
    const _Float16* __restrict__ vt, const float* __restrict__ Cw,
    float* __restrict__ out, int h0) {
  __shared__ _Float16 khi_s[32 * KSTRIDE] __attribute__((aligned(16)));
  __shared__ _Float16 vt_s[256 * VSTRIDE] __attribute__((aligned(16)));
  __shared__ _Float16 p_s[4][16 * VSTRIDE] __attribute__((aligned(16)));
  const int tid = threadIdx.x, w = tid >> 6, lane = tid & 63;
  const int quad = lane >> 4, l15 = lane & 15;
  const int hb = blockIdx.y, h = h0 + (hb >> 3), b = hb & 7;
  const int qbase = blockIdx.x * 64;
  // q fragments in registers (softmax scale 1/16 folded into q projection)
  half8 qfh[8], qfl[8];
  {
    size_t qrow = (size_t)hb * S_ + qbase + w * 16 + l15;
    const _Float16* qh = qhi + qrow * 256 + quad * 8;
    const _Float16* ql = qlo + qrow * 256 + quad * 8;
#pragma unroll
    for (int ks = 0; ks < 8; ++ks) {
      qfh[ks] = *(const half8*)(qh + ks * 32);
      qfl[ks] = *(const half8*)(ql + ks * 32);
    }
  }
  const f32x4 fz = {0.f, 0.f, 0.f, 0.f};
  f32x4 o_acc[16];
#pragma unroll
  for (int df = 0; df < 16; ++df) o_acc[df] = fz;
  float m_r[4], l_r[4];
#pragma unroll
  for (int r = 0; r < 4; ++r) { m_r[r] = -3.0e38f; l_r[r] = 0.f; }

  for (int kt = 0; kt < 64; ++kt) {
    __syncthreads();  // prior iteration's PV reads of k/v LDS are done
    {
      size_t kbase = ((size_t)hb * S_ + kt * 32) * 256;
#pragma unroll
      for (int i = 0; i < 4; ++i) {
        int cc = i * 256 + tid;
        int kr = cc >> 5, kch = (cc & 31) * 8;
        *(half8*)&khi_s[kr * KSTRIDE + kch] = *(const half8*)(khi + kbase + kr * 256 + kch);
        int vd = cc >> 2, vch = (cc & 3) * 8;
        size_t voff = ((size_t)hb * 256 + vd) * S_ + kt * 32 + vch;
        *(half8*)&vt_s[vd * VSTRIDE + vch] = *(const half8*)(vt + voff);
      }
    }
    __syncthreads();
    // QK^T: 2-mult (qh+ql)*kh, scores for 16 q-rows x 32 k-cols per wave
    f32x4 sc0 = fz, sc1 = fz;
#pragma unroll
    for (int ks = 0; ks < 8; ++ks) {
      half8 bh0 = *(const half8*)&khi_s[(0 * 16 + l15) * KSTRIDE + ks * 32 + quad * 8];
      sc0 = __builtin_amdgcn_mfma_f32_16x16x32_f16(qfh[ks], bh0, sc0, 0, 0, 0);
      sc0 = __builtin_amdgcn_mfma_f32_16x16x32_f16(qfl[ks], bh0, sc0, 0, 0, 0);
      half8 bh1 = *(const half8*)&khi_s[(1 * 16 + l15) * KSTRIDE + ks * 32 + quad * 8];
      sc1 = __builtin_amdgcn_mfma_f32_16x16x32_f16(qfh[ks], bh1, sc1, 0, 0, 0);
      sc1 = __builtin_amdgcn_mfma_f32_16x16x32_f16(qfl[ks], bh1, sc1, 0, 0, 0);
    }
    // online softmax; C/D layout: row = quad*4+r, col = lane&15
    float al[4], p0[4], p1[4];
#pragma unroll
    for (int r = 0; r < 4; ++r) {
      float v = fmaxf(sc0[r], sc1[r]);
      v = fmaxf(v, __shfl_xor(v, 1));
      v = fmaxf(v, __shfl_xor(v, 2));
      v = fmaxf(v, __shfl_xor(v, 4));
      v = fmaxf(v, __shfl_xor(v, 8));
      float mn = fmaxf(m_r[r], v);
      al[r] = __expf(m_r[r] - mn);
      m_r[r] = mn;
      p0[r] = __expf(sc0[r] - mn);
      p1[r] = __expf(sc1[r] - mn);
      float s = p0[r] + p1[r];
      s += __shfl_xor(s, 1);
      s += __shfl_xor(s, 2);
      s += __shfl_xor(s, 4);
      s += __shfl_xor(s, 8);
      l_r[r] = l_r[r] * al[r] + s;
    }
    // P -> LDS (C-layout write)
#pragma unroll
    for (int r = 0; r < 4; ++r) {
      p_s[w][(quad * 4 + r) * VSTRIDE + l15] = (_Float16)p0[r];
      p_s[w][(quad * 4 + r) * VSTRIDE + 16 + l15] = (_Float16)p1[r];
    }
    // rescale O accumulator
#pragma unroll
    for (int df = 0; df < 16; ++df)
#pragma unroll
      for (int r = 0; r < 4; ++r) o_acc[df][r] *= al[r];
    __syncthreads();  // phase barrier: keeps softmax-shuffle and PV LDS phases aligned
    // PV: P in A-layout from LDS, V^T as B operand
    half8 pf = *(const half8*)&p_s[w][l15 * VSTRIDE + quad * 8];
#pragma unroll
    for (int df = 0; df < 16; ++df) {
      half8 vf = *(const half8*)&vt_s[(df * 16 + l15) * VSTRIDE + quad * 8];
      o_acc[df] = __builtin_amdgcn_mfma_f32_16x16x32_f16(pf, vf, o_acc[df], 0, 0, 0);
    }
  }
  // epilogue: normalize + fused C-projection out[b,s,j] += sum_d o*Cw
  float rcl[4];
#pragma unroll
  for (int r = 0; r < 4; ++r) rcl[r] = 1.0f / l_r[r];
  float part[32];
#pragma unroll
  for (int i = 0; i < 32; ++i) part[i] = 0.f;
#pragma unroll
  for (int df = 0; df < 16; ++df) {
    const float4* cwv = (const float4*)(Cw + ((size_t)h * 256 + df * 16 + l15) * 8);
    float4 c0 = cwv[0], c1 = cwv[1];
#pragma unroll
    for (int r = 0; r < 4; ++r) {
      float ov = o_acc[df][r] * rcl[r];
      part[r * 8 + 0] += ov * c0.x;
      part[r * 8 + 1] += ov * c0.y;
      part[r * 8 + 2] += ov * c0.z;
      part[r * 8 + 3] += ov * c0.w;
      part[r * 8 + 4] += ov * c1.x;
      part[r * 8 + 5] += ov * c1.y;
      part[r * 8 + 6] += ov * c1.z;
      part[r * 8 + 7] += ov * c1.w;
    }
  }
#pragma unroll
  for (int i = 0; i < 32; ++i) {
    float v = part[i];
    v += __shfl_xor(v, 1);
    v += __shfl_xor(v, 2);
    v += __shfl_xor(v, 4);
    v += __shfl_xor(v, 8);
    part[i] = v;
  }
  if (l15 == 0) {
#pragma unroll
    for (int r = 0; r < 4; ++r) {
      int s = qbase + w * 16 + quad * 4 + r;
#pragma unroll
      for (int j = 0; j < 8; ++j)
        atomicAdd(&out[((size_t)b * S_ + s) * 8 + j], part[r * 8 + j]);
    }
  }
}

extern "C" void kernel_launch(void* const* d_in, const int* in_sizes, int n_in,
                              void* d_out, int out_size, void* d_ws, size_t ws_size,
                              hipStream_t stream) {
  const float* x  = (const float*)d_in[0];
  const float* bo = (const float*)d_in[1];
  const float* Qw = (const float*)d_in[2];
  const float* Qb = (const float*)d_in[3];
  const float* Kw = (const float*)d_in[4];
  const float* Kb = (const float*)d_in[5];
  const float* Vw = (const float*)d_in[6];
  const float* Vb = (const float*)d_in[7];
  const float* Cw = (const float*)d_in[8];
  const float* Cb = (const float*)d_in[9];
  float* out = (float*)d_out;

  const size_t NW  = (size_t)H_ * 256 * 256;
  const size_t NHB = (size_t)B_ * S_ * 256;
  const size_t ALN = 256;
  auto pad = [](size_t b) { return (b + 255) & ~(size_t)255; };

  // pick largest head-chunk HC in {8,4,2,1} whose scratch fits ws_size
  int HC = 8;
  while (HC > 1) {
    size_t need = 6 * pad(NW * 2) + 4 * pad((size_t)HC * NHB * 2) + ALN;
    if (need <= ws_size) break;
    HC >>= 1;
  }

  char* base = (char*)d_ws;
  size_t off = 0;
  auto carve = [&](size_t nelem) -> _Float16* {
    _Float16* p = (_Float16*)(base + off);
    off += pad(nelem * 2);
    return p;
  };
  _Float16* qwt_hi = carve(NW); _Float16* qwt_lo = carve(NW);
  _Float16* kwt_hi = carve(NW); _Float16* kwt_lo = carve(NW);
  _Float16* vwt_hi = carve(NW); _Float16* vwt_lo = carve(NW);
  const size_t NC = (size_t)HC * NHB;
  _Float16* q_hi = carve(NC); _Float16* q_lo = carve(NC);
  _Float16* k_hi = carve(NC);
  _Float16* v_t  = carve(NC);

  dim3 wg(4, 4, 8);
  split_w_kernel<<<wg, 256, 0, stream>>>(Qw, qwt_hi, qwt_lo);
  split_w_kernel<<<wg, 256, 0, stream>>>(Kw, kwt_hi, kwt_lo);
  split_w_kernel<<<wg, 256, 0, stream>>>(Vw, vwt_hi, vwt_lo);
  out_init_kernel<<<(B_ * S_ * 8) / 256, 256, 0, stream>>>(out, Cb);

  for (int h0 = 0; h0 < H_; h0 += HC) {
    dim3 pg(16, 2, HC * 8);
    // q: fold softmax scale 1/sqrt(256)=1/16 into the projection output
    proj_kernel<0><<<pg, 256, 0, stream>>>(bo, qwt_hi, qwt_lo, Qb, 0.0625f, h0, q_hi, q_lo);
    proj_kernel<2><<<pg, 256, 0, stream>>>(x, kwt_hi, kwt_lo, Kb, 1.0f, h0, k_hi, nullptr);
    proj_kernel<1><<<pg, 256, 0, stream>>>(x, vwt_hi, vwt_lo, Vb, 1.0f, h0, v_t, nullptr);
    dim3 fg(32, HC * 8);
    flash_kernel<<<fg, 256, 0, stream>>>(q_hi, q_lo, k_hi, v_t, Cw, out, h0);
  }
}